// Round 1
// baseline (1032.259 us; speedup 1.0000x reference)
//
#include <hip/hip_runtime.h>
#include <hip/hip_bf16.h>
#include <math.h>
#include <stdint.h>

#define VV 20000
#define LL 128
#define DD 256
#define DEMO_ 70
#define HID_ 1024
#define NN 2048

// ---- bf16 helpers (bit-level, OCP bf16 = truncated fp32 with RNE) ----
__device__ __forceinline__ float blo(uint32_t p) {
    union { uint32_t u; float f; } c; c.u = p << 16; return c.f;
}
__device__ __forceinline__ float bhi(uint32_t p) {
    union { uint32_t u; float f; } c; c.u = p & 0xffff0000u; return c.f;
}
__device__ __forceinline__ uint32_t f2bf(float f) {
    union { float f; uint32_t u; } c; c.f = f;
    return (c.u + 0x7fffu + ((c.u >> 16) & 1u)) >> 16;   // round-nearest-even
}

// ---- kernel 0: init output with reg_loss ----
__global__ void k_init(const float* ca, const float* cp, float* out) {
    if (threadIdx.x == 0) out[0] = ca[0] * ca[0] + cp[0] * cp[0];
}

// ---- kernel 1: M = Wq @ Wk^T  [DD x DD] fp32 into workspace ----
__global__ __launch_bounds__(256) void k_M(const float* __restrict__ Wq,
                                           const float* __restrict__ Wk,
                                           float* __restrict__ M) {
    __shared__ float wq_s[DD];
    int e = blockIdx.x, t = threadIdx.x;
    wq_s[t] = Wq[(size_t)e * DD + t];
    __syncthreads();
    const float4* wk4 = (const float4*)(Wk + (size_t)t * DD);
    const float4* wq4 = (const float4*)wq_s;
    float4 acc = make_float4(0.f, 0.f, 0.f, 0.f);
    for (int c = 0; c < DD / 4; ++c) {
        float4 a = wq4[c]; float4 b = wk4[c];
        acc.x += a.x * b.x; acc.y += a.y * b.y;
        acc.z += a.z * b.z; acc.w += a.w * b.w;
    }
    M[(size_t)e * DD + t] = acc.x + acc.y + acc.z + acc.w;
}

// ---- kernel 2: fused per-sample pipeline. One 256-thread block per sample ----
__global__ __launch_bounds__(256) void k_main(
    const float* __restrict__ E,   const float* __restrict__ Wv,
    const float* __restrict__ W1,  const float* __restrict__ b1,
    const float* __restrict__ W2,  const float* __restrict__ b2,
    const float* __restrict__ demo, const float* __restrict__ ht,
    const float* __restrict__ evt_t, const float* __restrict__ labels,
    const int* __restrict__ codes, const int* __restrict__ lens,
    const float* __restrict__ ca_p, const float* __restrict__ cp_p,
    const float* __restrict__ M,   float* __restrict__ out)
{
    // emb stride 260 halfwords (520 B): 8B-aligned rows, 2-way (free) bank pattern
    __shared__ unsigned short emb_s[LL][260];
    __shared__ float g_s[4][260];
    __shared__ float times_s[LL];
    __shared__ int   codes_s[LL];
    __shared__ float w_s[LL];
    __shared__ float a_s[4][LL];
    __shared__ float rp_s[DD];
    __shared__ float x_s[DEMO_ + DD + 2];
    __shared__ float red_s[4];

    const int n = blockIdx.x;
    const int tid = threadIdx.x, wv = tid >> 6, ln = tid & 63;
    const int len = lens[n];
    const float ca = ca_p[0], cp = cp_p[0];
    const float evt = evt_t[n];

    if (tid < LL && tid < len) {
        times_s[tid] = ht[(size_t)n * LL + tid];
        codes_s[tid] = codes[(size_t)n * LL + tid];
    }
    __syncthreads();

    // ---- pooling softmax weights w_i (all waves compute redundantly, wave0 writes)
    {
        float u0 = (ln      < len) ? cp * (times_s[ln]      - evt) : -1e30f;
        float u1 = (ln + 64 < len) ? cp * (times_s[ln + 64] - evt) : -1e30f;
        float mx = fmaxf(u0, u1);
        for (int o = 32; o; o >>= 1) mx = fmaxf(mx, __shfl_xor(mx, o, 64));
        float e0 = (ln      < len) ? __expf(u0 - mx) : 0.f;
        float e1 = (ln + 64 < len) ? __expf(u1 - mx) : 0.f;
        float sm = e0 + e1;
        for (int o = 32; o; o >>= 1) sm += __shfl_xor(sm, o, 64);
        if (wv == 0) {
            if (ln      < len) w_s[ln]      = e0 / sm;
            if (ln + 64 < len) w_s[ln + 64] = e1 / sm;
        }
    }

    // ---- gather E rows -> bf16 LDS (two rows per iteration, float2 loads)
    {
        int half = tid >> 7, t2 = tid & 127;
        for (int base = 0; base < len; base += 2) {
            int l = base + half;
            if (l < len) {
                const float2* src = (const float2*)(E + (size_t)codes_s[l] * DD);
                float2 v = src[t2];
                uint32_t pk = f2bf(v.x) | (f2bf(v.y) << 16);
                *(uint32_t*)&emb_s[l][2 * t2] = pk;
            }
        }
    }
    __syncthreads();

    // ---- main attention loop: wave wv owns rows i = wv, wv+4, ... (4-row register blocks)
    float a0 = 0.f, a1 = 0.f;            // column accumulators for j = ln, ln+64
    const float4* M4 = (const float4*)M;
    for (int i0 = wv; i0 < len; i0 += 16) {
        int r0 = i0 & (LL - 1), r1 = (i0 + 4) & (LL - 1),
            r2 = (i0 + 8) & (LL - 1), r3 = (i0 + 12) & (LL - 1);
        float4 acc[4];
        #pragma unroll
        for (int k = 0; k < 4; ++k) acc[k] = make_float4(0.f, 0.f, 0.f, 0.f);

        // Phase B: G rows = emb_row @ M  (lane ln owns d = 4ln..4ln+3)
        for (int e = 0; e < DD; e += 2) {
            float4 m0 = M4[(size_t)e * 64 + ln];
            float4 m1 = M4[(size_t)(e + 1) * 64 + ln];
            int rr[4] = { r0, r1, r2, r3 };
            #pragma unroll
            for (int k = 0; k < 4; ++k) {
                uint32_t p = *(const uint32_t*)&emb_s[rr[k]][e];
                float aa = blo(p), bb = bhi(p);
                acc[k].x += aa * m0.x; acc[k].y += aa * m0.y;
                acc[k].z += aa * m0.z; acc[k].w += aa * m0.w;
                acc[k].x += bb * m1.x; acc[k].y += bb * m1.y;
                acc[k].z += bb * m1.z; acc[k].w += bb * m1.w;
            }
        }

        // Phase C: per row — scores, online softmax, accumulate a_j
        #pragma unroll
        for (int k = 0; k < 4; ++k) {
            int i = i0 + 4 * k;
            if (i >= len) break;                       // wave-uniform
            *(float4*)&g_s[wv][4 * ln] = acc[k];       // within-wave LDS handoff
            float ti = times_s[i];
            float s0 = 0.f, s1 = 0.f;
            for (int e = 0; e < DD; e += 4) {
                float4 g = *(const float4*)&g_s[wv][e];          // broadcast
                uint2 pa = *(const uint2*)&emb_s[ln][e];
                uint2 pb = *(const uint2*)&emb_s[ln + 64][e];
                s0 += g.x * blo(pa.x) + g.y * bhi(pa.x) + g.z * blo(pa.y) + g.w * bhi(pa.y);
                s1 += g.x * blo(pb.x) + g.y * bhi(pb.x) + g.z * blo(pb.y) + g.w * bhi(pb.y);
            }
            s0 = (ln      < len) ? s0 * 0.0625f - ca * fabsf(ti - times_s[ln])      : -1e30f;
            s1 = (ln + 64 < len) ? s1 * 0.0625f - ca * fabsf(ti - times_s[ln + 64]) : -1e30f;
            float mx = fmaxf(s0, s1);
            for (int o = 32; o; o >>= 1) mx = fmaxf(mx, __shfl_xor(mx, o, 64));
            float p0 = __expf(s0 - mx), p1 = __expf(s1 - mx);
            float rs = p0 + p1;
            for (int o = 32; o; o >>= 1) rs += __shfl_xor(rs, o, 64);
            float sc = w_s[i] / rs;                    // fold w_i and row-softmax denom
            a0 += sc * p0; a1 += sc * p1;
        }
    }

    a_s[wv][ln] = a0; a_s[wv][ln + 64] = a1;
    __syncthreads();
    if (tid < LL)
        a_s[0][tid] = a_s[0][tid] + a_s[1][tid] + a_s[2][tid] + a_s[3][tid];
    __syncthreads();

    // ---- Phase D: rp = a @ emb  (thread tid owns dim d = tid)
    {
        float acc = 0.f;
        for (int j = 0; j < len; ++j)
            acc += a_s[0][j] * blo((uint32_t)emb_s[j][tid]);
        rp_s[tid] = acc;
    }
    __syncthreads();

    // ---- Phase E: repr = rp @ Wv ; build MLP input x = [demo, repr]
    {
        float acc = 0.f;
        for (int e = 0; e < DD; ++e)
            acc += rp_s[e] * Wv[(size_t)e * DD + tid];
        x_s[DEMO_ + tid] = acc;
        if (tid < DEMO_) x_s[tid] = demo[(size_t)n * DEMO_ + tid];
    }
    __syncthreads();

    // ---- Phase F: MLP + BCE loss
    {
        float4 acc = *(const float4*)&b1[4 * tid];     // j = 4t..4t+3
        const float4* W1r = (const float4*)W1;
        for (int x = 0; x < DEMO_ + DD; ++x) {
            float xv = x_s[x];
            float4 w = W1r[(size_t)x * (HID_ / 4) + tid];
            acc.x += xv * w.x; acc.y += xv * w.y;
            acc.z += xv * w.z; acc.w += xv * w.w;
        }
        acc.x = fmaxf(acc.x, 0.f); acc.y = fmaxf(acc.y, 0.f);
        acc.z = fmaxf(acc.z, 0.f); acc.w = fmaxf(acc.w, 0.f);
        float4 w2 = *(const float4*)&W2[4 * tid];
        float part = acc.x * w2.x + acc.y * w2.y + acc.z * w2.z + acc.w * w2.w;
        for (int o = 32; o; o >>= 1) part += __shfl_xor(part, o, 64);
        if (ln == 0) red_s[wv] = part;
        __syncthreads();
        if (tid == 0) {
            float z = red_s[0] + red_s[1] + red_s[2] + red_s[3] + b2[0];
            float y = labels[n];
            float lg = log1pf(__expf(-fabsf(z)));
            float spn = fmaxf(-z, 0.f) + lg;           // softplus(-z)
            float spp = fmaxf( z, 0.f) + lg;           // softplus(z)
            float loss = 2.f * y * spn + (1.f - y) * spp;
            atomicAdd(out, loss * (1.f / (float)NN));
        }
    }
}

extern "C" void kernel_launch(void* const* d_in, const int* in_sizes, int n_in,
                              void* d_out, int out_size, void* d_ws, size_t ws_size,
                              hipStream_t stream) {
    const float* E      = (const float*)d_in[0];
    const float* Wq     = (const float*)d_in[1];
    const float* Wk     = (const float*)d_in[2];
    const float* Wv     = (const float*)d_in[3];
    const float* ca     = (const float*)d_in[4];
    const float* cp     = (const float*)d_in[5];
    const float* W1     = (const float*)d_in[6];
    const float* b1     = (const float*)d_in[7];
    const float* W2     = (const float*)d_in[8];
    const float* b2     = (const float*)d_in[9];
    const float* demo   = (const float*)d_in[10];
    const float* ht     = (const float*)d_in[11];
    const float* evt    = (const float*)d_in[12];
    const float* labels = (const float*)d_in[13];
    const int*   codes  = (const int*)d_in[14];
    const int*   lens   = (const int*)d_in[15];
    float* out = (float*)d_out;
    float* M   = (float*)d_ws;          // 256*256*4 = 256 KB

    hipLaunchKernelGGL(k_init, dim3(1), dim3(64), 0, stream, ca, cp, out);
    hipLaunchKernelGGL(k_M, dim3(DD), dim3(DD), 0, stream, Wq, Wk, M);
    hipLaunchKernelGGL(k_main, dim3(NN), dim3(256), 0, stream,
                       E, Wv, W1, b1, W2, b2, demo, ht, evt, labels,
                       codes, lens, ca, cp, M, out);
}

// Round 2
// 400.245 us; speedup vs baseline: 2.5791x; 2.5791x over previous
//
#include <hip/hip_runtime.h>
#include <hip/hip_bf16.h>
#include <math.h>
#include <stdint.h>

#define VV 20000
#define LL 128
#define DD 256
#define DEMO_ 70
#define HID_ 1024
#define NN 2048

typedef __attribute__((ext_vector_type(8))) short short8;
typedef __attribute__((ext_vector_type(4))) float f32x4;

// ---- bf16 helpers ----
__device__ __forceinline__ float bf2f(uint32_t u) {
    union { uint32_t u; float f; } c; c.u = u << 16; return c.f;
}
__device__ __forceinline__ uint32_t f2bf(float f) {
    union { float f; uint32_t u; } c; c.f = f;
    return (c.u + 0x7fffu + ((c.u >> 16) & 1u)) >> 16;   // RNE
}

// swizzled halfword offset inside a [128][256] bf16 LDS tile:
// 16B blocks within a row are XORed with (row&7) -> conflict-free b128 frags
__device__ __forceinline__ int sw_off(int row, int col) {
    return (row << 8) + ((((col >> 3) ^ (row & 7)) << 3) | (col & 7));
}

// ---- kernel 0: init output with reg_loss ----
__global__ void k_init(const float* ca, const float* cp, float* out) {
    if (threadIdx.x == 0) out[0] = ca[0] * ca[0] + cp[0] * cp[0];
}

// ---- kernel 1: Mx = Wq @ Wk^T  -> bf16 row-major [e][f] ----
__global__ __launch_bounds__(256) void k_M(const float* __restrict__ Wq,
                                           const float* __restrict__ Wk,
                                           unsigned short* __restrict__ Mx) {
    __shared__ float wq_s[DD];
    int e = blockIdx.x, t = threadIdx.x;
    wq_s[t] = Wq[(size_t)e * DD + t];
    __syncthreads();
    const float4* wk4 = (const float4*)(Wk + (size_t)t * DD);
    const float4* wq4 = (const float4*)wq_s;
    float4 acc = make_float4(0.f, 0.f, 0.f, 0.f);
    for (int c = 0; c < DD / 4; ++c) {
        float4 a = wq4[c]; float4 b = wk4[c];
        acc.x += a.x * b.x; acc.y += a.y * b.y;
        acc.z += a.z * b.z; acc.w += a.w * b.w;
    }
    Mx[(size_t)e * DD + t] = (unsigned short)f2bf(acc.x + acc.y + acc.z + acc.w);
}

// ---- kernel 2: W1eff^T bf16 [1024][352]:
// rows k<70: W1eT[h][k] = W1[k][h]; k>=70: W1eT[h][k] = sum_n Wv[k-70][n]*W1[70+n][h]
__global__ __launch_bounds__(256) void k_prep(const float* __restrict__ Wv,
                                              const float* __restrict__ W1,
                                              unsigned short* __restrict__ W1eT) {
    __shared__ float wv_s[DD];
    int k = blockIdx.x, t = threadIdx.x;
    if (k < DEMO_) {
        #pragma unroll
        for (int hh = 0; hh < 4; ++hh) {
            int h = t + 256 * hh;
            W1eT[(size_t)h * 352 + k] = (unsigned short)f2bf(W1[(size_t)k * HID_ + h]);
        }
    } else {
        int e = k - DEMO_;
        wv_s[t] = Wv[(size_t)e * DD + t];
        __syncthreads();
        float acc0 = 0.f, acc1 = 0.f, acc2 = 0.f, acc3 = 0.f;
        for (int n = 0; n < DD; ++n) {
            float wvv = wv_s[n];
            const float* row = W1 + (size_t)(DEMO_ + n) * HID_;
            acc0 += wvv * row[t];
            acc1 += wvv * row[t + 256];
            acc2 += wvv * row[t + 512];
            acc3 += wvv * row[t + 768];
        }
        W1eT[(size_t)(t      ) * 352 + k] = (unsigned short)f2bf(acc0);
        W1eT[(size_t)(t + 256) * 352 + k] = (unsigned short)f2bf(acc1);
        W1eT[(size_t)(t + 512) * 352 + k] = (unsigned short)f2bf(acc2);
        W1eT[(size_t)(t + 768) * 352 + k] = (unsigned short)f2bf(acc3);
    }
}

// ---- kernel 3: per-sample attention+pooling -> rp (bf16) ----
__global__ __launch_bounds__(256, 1) void k_main(
    const float* __restrict__ E,
    const float* __restrict__ ht,  const float* __restrict__ evt_t,
    const int* __restrict__ codes, const int* __restrict__ lens,
    const float* __restrict__ ca_p, const float* __restrict__ cp_p,
    const unsigned short* __restrict__ Mx,
    unsigned short* __restrict__ Rbf)
{
    __shared__ __align__(16) unsigned short emb_u[LL * DD];   // 64 KB, swizzled
    __shared__ __align__(16) float uhs[LL * 129];             // 66 KB: H(bf16) then S(fp32)
    __shared__ float times_s[LL];
    __shared__ int   codes_s[LL];
    __shared__ float w_s[LL];
    __shared__ float a_s[4][LL];
    __shared__ float asum[LL];

    unsigned short* H_u = (unsigned short*)uhs;
    float* S_f = uhs;

    const int n = blockIdx.x;
    const int tid = threadIdx.x, wv = tid >> 6, ln = tid & 63;
    const int q = ln >> 4, m = ln & 15;
    const int len = lens[n];
    const int it_n = (len + 15) >> 4;          // row tiles (== col tiles)
    const float ca = ca_p[0], cp = cp_p[0];
    const float evt = evt_t[n];

    if (tid < LL && tid < len) {
        times_s[tid] = ht[(size_t)n * LL + tid];
        codes_s[tid] = codes[(size_t)n * LL + tid];
    }
    __syncthreads();

    // ---- gather E rows -> swizzled bf16 LDS (4 rows/iter, float4 loads)
    for (int l0 = 0; l0 < len; l0 += 4) {
        int l = l0 + wv;
        if (l < len) {
            const float4* src = (const float4*)(E + (size_t)codes_s[l] * DD);
            float4 v = src[ln];
            uint32_t lo = f2bf(v.x) | (f2bf(v.y) << 16);
            uint32_t hi = f2bf(v.z) | (f2bf(v.w) << 16);
            int off = sw_off(l, 4 * ln);
            *(uint2*)&emb_u[off] = make_uint2(lo, hi);
        }
    }
    // ---- pooling weights (wave 0)
    if (wv == 0) {
        float u0 = (ln      < len) ? cp * (times_s[ln]      - evt) : 0.f;
        float u1 = (ln + 64 < len) ? cp * (times_s[ln + 64] - evt) : 0.f;
        float e0 = (ln      < len) ? __expf(u0) : 0.f;
        float e1 = (ln + 64 < len) ? __expf(u1) : 0.f;
        float sm = e0 + e1;
        for (int o = 32; o; o >>= 1) sm += __shfl_xor(sm, o, 64);
        float inv = 1.f / sm;
        if (ln      < len) w_s[ln]      = e0 * inv;
        if (ln + 64 < len) w_s[ln + 64] = e1 * inv;
    }
    __syncthreads();

    // ---- phase B: H[i][n'] = sum_f emb[i][f] * Mx[n'][f]   (H = emb @ Mx^T)
    // wave wv owns output cols n' in [64*wv, 64*wv+64)
    short8 bB[32];
    #pragma unroll
    for (int kk = 0; kk < 8; ++kk)
        #pragma unroll
        for (int nt = 0; nt < 4; ++nt) {
            int mrow = wv * 64 + nt * 16 + m;
            bB[kk * 4 + nt] = *(const short8*)(Mx + (size_t)mrow * DD + kk * 32 + q * 8);
        }
    for (int it = 0; it < it_n; ++it) {
        f32x4 hacc[4];
        #pragma unroll
        for (int nt = 0; nt < 4; ++nt) hacc[nt] = (f32x4)0.f;
        #pragma unroll
        for (int kk = 0; kk < 8; ++kk) {
            short8 af = *(const short8*)&emb_u[sw_off(it * 16 + m, kk * 32 + q * 8)];
            #pragma unroll
            for (int nt = 0; nt < 4; ++nt)
                hacc[nt] = __builtin_amdgcn_mfma_f32_16x16x32_bf16(af, bB[kk * 4 + nt], hacc[nt], 0, 0, 0);
        }
        #pragma unroll
        for (int nt = 0; nt < 4; ++nt)
            #pragma unroll
            for (int r = 0; r < 4; ++r) {
                int row = it * 16 + q * 4 + r;
                int col = wv * 64 + nt * 16 + m;
                H_u[sw_off(row, col)] = (unsigned short)f2bf(hacc[nt][r]);
            }
    }
    __syncthreads();

    // ---- phase C: S[i][j] = sum_e emb[i][e] * H[j][e]   (kept in regs)
    f32x4 sacc[8][2];
    #pragma unroll
    for (int it = 0; it < 8; ++it) { sacc[it][0] = (f32x4)0.f; sacc[it][1] = (f32x4)0.f; }
    #pragma unroll
    for (int jj = 0; jj < 2; ++jj) {
        int jt = wv + 4 * jj;
        if (jt < it_n) {
            short8 bH[8];
            #pragma unroll
            for (int kk = 0; kk < 8; ++kk)
                bH[kk] = *(const short8*)&H_u[sw_off(jt * 16 + m, kk * 32 + q * 8)];
            #pragma unroll
            for (int it = 0; it < 8; ++it) {
                if (it < it_n) {
                    #pragma unroll
                    for (int kk = 0; kk < 8; ++kk) {
                        short8 af = *(const short8*)&emb_u[sw_off(it * 16 + m, kk * 32 + q * 8)];
                        sacc[it][jj] = __builtin_amdgcn_mfma_f32_16x16x32_bf16(af, bH[kk], sacc[it][jj], 0, 0, 0);
                    }
                }
            }
        }
    }
    __syncthreads();                     // all H reads done; S may overwrite H

    #pragma unroll
    for (int jj = 0; jj < 2; ++jj) {
        int jt = wv + 4 * jj;
        if (jt < it_n) {
            #pragma unroll
            for (int it = 0; it < 8; ++it) {
                if (it < it_n) {
                    #pragma unroll
                    for (int r = 0; r < 4; ++r)
                        S_f[(it * 16 + q * 4 + r) * 129 + jt * 16 + m] = sacc[it][jj][r];
                }
            }
        }
    }
    __syncthreads();

    // ---- softmax + column accumulation: a_j = sum_i w_i * attn_ij
    {
        float tj0 = times_s[ln], tj1 = times_s[ln + 64];
        bool v0 = ln < len, v1 = (ln + 64) < len;
        float a0 = 0.f, a1 = 0.f;
        for (int i = wv; i < len; i += 4) {
            float ti = times_s[i];
            float s0 = S_f[i * 129 + ln];
            float s1 = S_f[i * 129 + ln + 64];
            float p0 = v0 ? __expf(s0 * 0.0625f - ca * fabsf(ti - tj0)) : 0.f;
            float p1 = v1 ? __expf(s1 * 0.0625f - ca * fabsf(ti - tj1)) : 0.f;
            float rs = p0 + p1;
            for (int o = 32; o; o >>= 1) rs += __shfl_xor(rs, o, 64);
            float sc = w_s[i] / rs;
            a0 += sc * p0; a1 += sc * p1;
        }
        a_s[wv][ln] = a0; a_s[wv][ln + 64] = a1;
    }
    __syncthreads();
    if (tid < LL) asum[tid] = a_s[0][tid] + a_s[1][tid] + a_s[2][tid] + a_s[3][tid];
    __syncthreads();

    // ---- phase D: rp[d] = sum_j a_j * emb[j][d] -> bf16 ws
    {
        float racc = 0.f;
        for (int j = 0; j < len; ++j)
            racc += asum[j] * bf2f(emb_u[sw_off(j, tid)]);
        Rbf[(size_t)n * DD + tid] = (unsigned short)f2bf(racc);
    }
}

// ---- kernel 4: batched MLP (MFMA) + BCE loss. 16 samples/block ----
__global__ __launch_bounds__(256) void k_mlp(
    const float* __restrict__ demo, const float* __restrict__ labels,
    const float* __restrict__ b1,   const float* __restrict__ W2,
    const float* __restrict__ b2,
    const unsigned short* __restrict__ Rbf,
    const unsigned short* __restrict__ W1eT,
    float* __restrict__ out)
{
    __shared__ __align__(16) unsigned short xs[16][360];   // K padded to 352, stride 360
    __shared__ float W2s[HID_];
    __shared__ float b1s[HID_];
    __shared__ float wred[4][16];
    __shared__ float lred[16];

    const int tid = threadIdx.x, wv = tid >> 6, ln = tid & 63;
    const int q = ln >> 4, m = ln & 15;
    const int s0 = blockIdx.x * 16;

    #pragma unroll
    for (int hh = 0; hh < 4; ++hh) {
        W2s[tid + 256 * hh] = W2[tid + 256 * hh];
        b1s[tid + 256 * hh] = b1[tid + 256 * hh];
    }
    for (int s = 0; s < 16; ++s) {
        if (tid < DEMO_) xs[s][tid] = (unsigned short)f2bf(demo[(size_t)(s0 + s) * DEMO_ + tid]);
        xs[s][DEMO_ + tid] = Rbf[(size_t)(s0 + s) * DD + tid];
        if (tid < 34) xs[s][326 + tid] = 0;
    }
    __syncthreads();

    f32x4 cacc[16];
    #pragma unroll
    for (int ntl = 0; ntl < 16; ++ntl) cacc[ntl] = (f32x4)0.f;

    for (int kk = 0; kk < 11; ++kk) {
        short8 af = *(const short8*)&xs[m][kk * 32 + q * 8];
        #pragma unroll
        for (int ntl = 0; ntl < 16; ++ntl) {
            int h = wv * 256 + ntl * 16 + m;
            short8 bfd = *(const short8*)(W1eT + (size_t)h * 352 + kk * 32 + q * 8);
            cacc[ntl] = __builtin_amdgcn_mfma_f32_16x16x32_bf16(af, bfd, cacc[ntl], 0, 0, 0);
        }
    }

    float ls0 = 0.f, ls1 = 0.f, ls2 = 0.f, ls3 = 0.f;
    #pragma unroll
    for (int ntl = 0; ntl < 16; ++ntl) {
        int h = wv * 256 + ntl * 16 + m;
        float bb = b1s[h], w2v = W2s[h];
        ls0 += fmaxf(cacc[ntl][0] + bb, 0.f) * w2v;
        ls1 += fmaxf(cacc[ntl][1] + bb, 0.f) * w2v;
        ls2 += fmaxf(cacc[ntl][2] + bb, 0.f) * w2v;
        ls3 += fmaxf(cacc[ntl][3] + bb, 0.f) * w2v;
    }
    #pragma unroll
    for (int o = 1; o <= 8; o <<= 1) {
        ls0 += __shfl_xor(ls0, o, 64); ls1 += __shfl_xor(ls1, o, 64);
        ls2 += __shfl_xor(ls2, o, 64); ls3 += __shfl_xor(ls3, o, 64);
    }
    if (m == 0) {
        wred[wv][q * 4 + 0] = ls0; wred[wv][q * 4 + 1] = ls1;
        wred[wv][q * 4 + 2] = ls2; wred[wv][q * 4 + 3] = ls3;
    }
    __syncthreads();
    if (tid < 16) {
        float z = wred[0][tid] + wred[1][tid] + wred[2][tid] + wred[3][tid] + b2[0];
        float y = labels[s0 + tid];
        float lg = log1pf(__expf(-fabsf(z)));
        float loss = 2.f * y * (fmaxf(-z, 0.f) + lg) + (1.f - y) * (fmaxf(z, 0.f) + lg);
        lred[tid] = loss;
    }
    __syncthreads();
    if (tid == 0) {
        float t = 0.f;
        #pragma unroll
        for (int i = 0; i < 16; ++i) t += lred[i];
        atomicAdd(out, t * (1.f / (float)NN));
    }
}

extern "C" void kernel_launch(void* const* d_in, const int* in_sizes, int n_in,
                              void* d_out, int out_size, void* d_ws, size_t ws_size,
                              hipStream_t stream) {
    const float* E      = (const float*)d_in[0];
    const float* Wq     = (const float*)d_in[1];
    const float* Wk     = (const float*)d_in[2];
    const float* Wv     = (const float*)d_in[3];
    const float* ca     = (const float*)d_in[4];
    const float* cp     = (const float*)d_in[5];
    const float* W1     = (const float*)d_in[6];
    const float* b1     = (const float*)d_in[7];
    const float* W2     = (const float*)d_in[8];
    const float* b2     = (const float*)d_in[9];
    const float* demo   = (const float*)d_in[10];
    const float* ht     = (const float*)d_in[11];
    const float* evt    = (const float*)d_in[12];
    const float* labels = (const float*)d_in[13];
    const int*   codes  = (const int*)d_in[14];
    const int*   lens   = (const int*)d_in[15];
    float* out = (float*)d_out;

    unsigned short* Mx   = (unsigned short*)d_ws;                          // 128 KB
    unsigned short* W1eT = (unsigned short*)((char*)d_ws + 131072);        // 704 KB
    unsigned short* Rbf  = (unsigned short*)((char*)d_ws + 851968);        // 1 MB

    hipLaunchKernelGGL(k_init, dim3(1), dim3(64), 0, stream, ca, cp, out);
    hipLaunchKernelGGL(k_M,    dim3(DD), dim3(DD), 0, stream, Wq, Wk, Mx);
    hipLaunchKernelGGL(k_prep, dim3(DD + DEMO_), dim3(256), 0, stream, Wv, W1, W1eT);
    hipLaunchKernelGGL(k_main, dim3(NN), dim3(256), 0, stream,
                       E, ht, evt, codes, lens, ca, cp, Mx, Rbf);
    hipLaunchKernelGGL(k_mlp,  dim3(NN / 16), dim3(256), 0, stream,
                       demo, labels, b1, W2, b2, Rbf, W1eT, out);
}

// Round 3
// 338.764 us; speedup vs baseline: 3.0471x; 1.1815x over previous
//
#include <hip/hip_runtime.h>
#include <hip/hip_bf16.h>
#include <math.h>
#include <stdint.h>

#define VV 20000
#define LL 128
#define DD 256
#define DEMO_ 70
#define HID_ 1024
#define NN 2048

typedef __attribute__((ext_vector_type(8))) short short8;
typedef __attribute__((ext_vector_type(4))) float f32x4;

// ---- bf16 helpers ----
__device__ __forceinline__ float bf2f(uint32_t u) {
    union { uint32_t u; float f; } c; c.u = u << 16; return c.f;
}
__device__ __forceinline__ uint32_t f2bf(float f) {
    union { float f; uint32_t u; } c; c.f = f;
    return (c.u + 0x7fffu + ((c.u >> 16) & 1u)) >> 16;   // RNE
}

// swizzled halfword offset inside a [128][256] bf16 LDS tile:
// 16B blocks within a row are XORed with (row&7) -> conflict-free b128 frags
__device__ __forceinline__ int sw_off(int row, int col) {
    return (row << 8) + ((((col >> 3) ^ (row & 7)) << 3) | (col & 7));
}

// ---- kernel 0: init output with reg_loss ----
__global__ void k_init(const float* ca, const float* cp, float* out) {
    if (threadIdx.x == 0) out[0] = ca[0] * ca[0] + cp[0] * cp[0];
}

// ---- kernel 1: Mx = Wq @ Wk^T  -> bf16 row-major ----
__global__ __launch_bounds__(256) void k_M(const float* __restrict__ Wq,
                                           const float* __restrict__ Wk,
                                           unsigned short* __restrict__ Mx) {
    __shared__ float wq_s[DD];
    int e = blockIdx.x, t = threadIdx.x;
    wq_s[t] = Wq[(size_t)e * DD + t];
    __syncthreads();
    const float4* wk4 = (const float4*)(Wk + (size_t)t * DD);
    const float4* wq4 = (const float4*)wq_s;
    float4 acc = make_float4(0.f, 0.f, 0.f, 0.f);
    for (int c = 0; c < DD / 4; ++c) {
        float4 a = wq4[c]; float4 b = wk4[c];
        acc.x += a.x * b.x; acc.y += a.y * b.y;
        acc.z += a.z * b.z; acc.w += a.w * b.w;
    }
    Mx[(size_t)e * DD + t] = (unsigned short)f2bf(acc.x + acc.y + acc.z + acc.w);
}

// ---- kernel 2: W1eff^T bf16 [1024][352] (4-way h-split grid) ----
__global__ __launch_bounds__(256) void k_prep(const float* __restrict__ Wv,
                                              const float* __restrict__ W1,
                                              unsigned short* __restrict__ W1eT) {
    __shared__ float wv_s[DD];
    int k = blockIdx.x, t = threadIdx.x;
    int h = t + 256 * blockIdx.y;
    if (k >= 326) {                      // zero padding cols 326..351
        W1eT[(size_t)h * 352 + k] = 0;
        return;
    }
    if (k < DEMO_) {
        W1eT[(size_t)h * 352 + k] = (unsigned short)f2bf(W1[(size_t)k * HID_ + h]);
    } else {
        int e = k - DEMO_;
        wv_s[t] = Wv[(size_t)e * DD + t];
        __syncthreads();
        float acc = 0.f;
        for (int n = 0; n < DD; ++n)
            acc += wv_s[n] * W1[(size_t)(DEMO_ + n) * HID_ + h];
        W1eT[(size_t)h * 352 + k] = (unsigned short)f2bf(acc);
    }
}

// ---- kernel 3: per-sample attention+pooling -> rp (bf16). 512 thr/block ----
__global__ __launch_bounds__(512, 1) void k_main(
    const float* __restrict__ E,
    const float* __restrict__ ht,  const float* __restrict__ evt_t,
    const int* __restrict__ codes, const int* __restrict__ lens,
    const float* __restrict__ ca_p, const float* __restrict__ cp_p,
    const unsigned short* __restrict__ Mx,
    unsigned short* __restrict__ Rbf)
{
    __shared__ __align__(16) unsigned short emb_u[LL * DD];   // 64 KB swizzled
    __shared__ __align__(16) unsigned short H_u[LL * DD];     // 64 KB swizzled
    __shared__ float times_s[LL];
    __shared__ int   codes_s[LL];
    __shared__ float w_s[LL];
    __shared__ float apart[8][LL];
    __shared__ float asum[LL];
    __shared__ float rp2[2][DD];

    const int n = blockIdx.x;
    const int tid = threadIdx.x, wv = tid >> 6, ln = tid & 63;
    const int q = ln >> 4, m = ln & 15;
    const int len = lens[n];
    const int it_n = (len + 15) >> 4;
    const float ca = ca_p[0], cp = cp_p[0];
    const float evt = evt_t[n];

    ((float*)apart)[tid]       = 0.f;
    ((float*)apart)[tid + 512] = 0.f;
    if (tid < LL) {
        w_s[tid] = 0.f;
        if (tid < len) {
            times_s[tid] = ht[(size_t)n * LL + tid];
            codes_s[tid] = codes[(size_t)n * LL + tid];
        }
    }
    __syncthreads();

    // ---- pooling weights (wave 0) + gather (all waves, 2 rows in flight)
    if (wv == 0) {
        float u0 = (ln      < len) ? cp * (times_s[ln]      - evt) : 0.f;
        float u1 = (ln + 64 < len) ? cp * (times_s[ln + 64] - evt) : 0.f;
        float e0 = (ln      < len) ? __expf(u0) : 0.f;
        float e1 = (ln + 64 < len) ? __expf(u1) : 0.f;
        float sm = e0 + e1;
        for (int o = 32; o; o >>= 1) sm += __shfl_xor(sm, o, 64);
        float inv = 1.f / sm;
        if (ln      < len) w_s[ln]      = e0 * inv;
        if (ln + 64 < len) w_s[ln + 64] = e1 * inv;
    }
    for (int l0 = wv; l0 < len; l0 += 16) {
        const float4* s0 = (const float4*)(E + (size_t)codes_s[l0] * DD);
        float4 v0 = s0[ln];
        int l1 = l0 + 8; bool has1 = l1 < len;
        float4 v1 = make_float4(0.f, 0.f, 0.f, 0.f);
        if (has1) v1 = ((const float4*)(E + (size_t)codes_s[l1] * DD))[ln];
        *(uint2*)&emb_u[sw_off(l0, 4 * ln)] =
            make_uint2(f2bf(v0.x) | (f2bf(v0.y) << 16), f2bf(v0.z) | (f2bf(v0.w) << 16));
        if (has1)
            *(uint2*)&emb_u[sw_off(l1, 4 * ln)] =
                make_uint2(f2bf(v1.x) | (f2bf(v1.y) << 16), f2bf(v1.z) | (f2bf(v1.w) << 16));
    }
    __syncthreads();

    // ---- phase B: H = emb @ Mx^T. wave wv owns cols [32wv, 32wv+32)
    short8 bB[2][8];
    #pragma unroll
    for (int nt = 0; nt < 2; ++nt)
        #pragma unroll
        for (int kk = 0; kk < 8; ++kk) {
            int mrow = wv * 32 + nt * 16 + m;
            bB[nt][kk] = *(const short8*)(Mx + (size_t)mrow * DD + kk * 32 + q * 8);
        }
    short8 aC[8];                                 // cached A-frags for row tile wv
    for (int it = 0; it < it_n; ++it) {
        f32x4 h0 = (f32x4)0.f, h1 = (f32x4)0.f;
        #pragma unroll
        for (int kk = 0; kk < 8; ++kk) {
            short8 af = *(const short8*)&emb_u[sw_off(it * 16 + m, kk * 32 + q * 8)];
            if (it == wv) aC[kk] = af;            // wave-uniform predicate
            h0 = __builtin_amdgcn_mfma_f32_16x16x32_bf16(af, bB[0][kk], h0, 0, 0, 0);
            h1 = __builtin_amdgcn_mfma_f32_16x16x32_bf16(af, bB[1][kk], h1, 0, 0, 0);
        }
        #pragma unroll
        for (int r = 0; r < 4; ++r) {
            int row = it * 16 + q * 4 + r;
            H_u[sw_off(row, wv * 32 + m)]      = (unsigned short)f2bf(h0[r]);
            H_u[sw_off(row, wv * 32 + 16 + m)] = (unsigned short)f2bf(h1[r]);
        }
    }
    __syncthreads();

    // ---- phase C: wave wv owns row tile it=wv. S in registers.
    if (wv < it_n) {
        f32x4 sac[8];
        #pragma unroll
        for (int jt = 0; jt < 8; ++jt) sac[jt] = (f32x4)0.f;
        for (int jt = 0; jt < it_n; ++jt) {
            #pragma unroll
            for (int kk = 0; kk < 8; ++kk) {
                short8 bH = *(const short8*)&H_u[sw_off(jt * 16 + m, kk * 32 + q * 8)];
                sac[jt] = __builtin_amdgcn_mfma_f32_16x16x32_bf16(aC[kk], bH, sac[jt], 0, 0, 0);
            }
        }
        // softmax + column accumulation, all in regs
        int i_base = wv * 16 + q * 4;
        float ti[4]; bool vR[4]; float rowsum[4];
        #pragma unroll
        for (int r = 0; r < 4; ++r) {
            vR[r] = (i_base + r) < len;
            ti[r] = times_s[i_base + r];
            rowsum[r] = 0.f;
        }
        int jcol_base = m;
        for (int jt = 0; jt < it_n; ++jt) {
            int jcol = jt * 16 + jcol_base;
            bool vC = jcol < len;
            float tj = times_s[jcol];
            #pragma unroll
            for (int r = 0; r < 4; ++r) {
                float arg = sac[jt][r] * 0.0625f - ca * fabsf(ti[r] - tj);
                float p = (vR[r] && vC) ? __expf(arg) : 0.f;
                sac[jt][r] = p;
                rowsum[r] += p;
            }
        }
        #pragma unroll
        for (int r = 0; r < 4; ++r) {
            float s = rowsum[r];
            s += __shfl_xor(s, 1, 64); s += __shfl_xor(s, 2, 64);
            s += __shfl_xor(s, 4, 64); s += __shfl_xor(s, 8, 64);
            rowsum[r] = s;
        }
        float sc[4];
        #pragma unroll
        for (int r = 0; r < 4; ++r)
            sc[r] = (vR[r] && rowsum[r] > 0.f) ? w_s[i_base + r] / rowsum[r] : 0.f;
        for (int jt = 0; jt < it_n; ++jt) {
            float v = sc[0] * sac[jt][0] + sc[1] * sac[jt][1]
                    + sc[2] * sac[jt][2] + sc[3] * sac[jt][3];
            v += __shfl_xor(v, 16, 64);
            v += __shfl_xor(v, 32, 64);
            if (q == 0) apart[wv][jt * 16 + m] = v;
        }
    }
    __syncthreads();

    if (tid < LL)
        asum[tid] = apart[0][tid] + apart[1][tid] + apart[2][tid] + apart[3][tid]
                  + apart[4][tid] + apart[5][tid] + apart[6][tid] + apart[7][tid];
    __syncthreads();

    // ---- phase D: rp[d] = sum_j a_j * emb[j][d], split j-range over 2 halves
    {
        int d = tid & 255, half = tid >> 8;
        int jb = half * 64, je = len < jb + 64 ? len : jb + 64;
        float racc = 0.f;
        for (int j = jb; j < je; ++j)
            racc += asum[j] * bf2f(emb_u[sw_off(j, d)]);
        rp2[half][d] = racc;
    }
    __syncthreads();
    if (tid < DD)
        Rbf[(size_t)n * DD + tid] = (unsigned short)f2bf(rp2[0][tid] + rp2[1][tid]);
}

// ---- kernel 4: batched MLP (MFMA) + BCE loss. 16 samples/block ----
__global__ __launch_bounds__(256) void k_mlp(
    const float* __restrict__ demo, const float* __restrict__ labels,
    const float* __restrict__ b1,   const float* __restrict__ W2,
    const float* __restrict__ b2,
    const unsigned short* __restrict__ Rbf,
    const unsigned short* __restrict__ W1eT,
    float* __restrict__ out)
{
    __shared__ __align__(16) unsigned short xs[16][360];
    __shared__ float W2s[HID_];
    __shared__ float b1s[HID_];
    __shared__ float wred[4][16];
    __shared__ float lred[16];

    const int tid = threadIdx.x, wv = tid >> 6, ln = tid & 63;
    const int q = ln >> 4, m = ln & 15;
    const int s0 = blockIdx.x * 16;

    #pragma unroll
    for (int hh = 0; hh < 4; ++hh) {
        W2s[tid + 256 * hh] = W2[tid + 256 * hh];
        b1s[tid + 256 * hh] = b1[tid + 256 * hh];
    }
    for (int s = 0; s < 16; ++s) {
        if (tid < DEMO_) xs[s][tid] = (unsigned short)f2bf(demo[(size_t)(s0 + s) * DEMO_ + tid]);
        xs[s][DEMO_ + tid] = Rbf[(size_t)(s0 + s) * DD + tid];
        if (tid < 34) xs[s][326 + tid] = 0;
    }
    __syncthreads();

    f32x4 cacc[16];
    #pragma unroll
    for (int ntl = 0; ntl < 16; ++ntl) cacc[ntl] = (f32x4)0.f;

    for (int kk = 0; kk < 11; ++kk) {
        short8 af = *(const short8*)&xs[m][kk * 32 + q * 8];
        #pragma unroll
        for (int ntl = 0; ntl < 16; ++ntl) {
            int h = wv * 256 + ntl * 16 + m;
            short8 bfd = *(const short8*)(W1eT + (size_t)h * 352 + kk * 32 + q * 8);
            cacc[ntl] = __builtin_amdgcn_mfma_f32_16x16x32_bf16(af, bfd, cacc[ntl], 0, 0, 0);
        }
    }

    float ls0 = 0.f, ls1 = 0.f, ls2 = 0.f, ls3 = 0.f;
    #pragma unroll
    for (int ntl = 0; ntl < 16; ++ntl) {
        int h = wv * 256 + ntl * 16 + m;
        float bb = b1s[h], w2v = W2s[h];
        ls0 += fmaxf(cacc[ntl][0] + bb, 0.f) * w2v;
        ls1 += fmaxf(cacc[ntl][1] + bb, 0.f) * w2v;
        ls2 += fmaxf(cacc[ntl][2] + bb, 0.f) * w2v;
        ls3 += fmaxf(cacc[ntl][3] + bb, 0.f) * w2v;
    }
    #pragma unroll
    for (int o = 1; o <= 8; o <<= 1) {
        ls0 += __shfl_xor(ls0, o, 64); ls1 += __shfl_xor(ls1, o, 64);
        ls2 += __shfl_xor(ls2, o, 64); ls3 += __shfl_xor(ls3, o, 64);
    }
    if (m == 0) {
        wred[wv][q * 4 + 0] = ls0; wred[wv][q * 4 + 1] = ls1;
        wred[wv][q * 4 + 2] = ls2; wred[wv][q * 4 + 3] = ls3;
    }
    __syncthreads();
    if (tid < 16) {
        float z = wred[0][tid] + wred[1][tid] + wred[2][tid] + wred[3][tid] + b2[0];
        float y = labels[s0 + tid];
        float lg = log1pf(__expf(-fabsf(z)));
        float loss = 2.f * y * (fmaxf(-z, 0.f) + lg) + (1.f - y) * (fmaxf(z, 0.f) + lg);
        lred[tid] = loss;
    }
    __syncthreads();
    if (tid == 0) {
        float t = 0.f;
        #pragma unroll
        for (int i = 0; i < 16; ++i) t += lred[i];
        atomicAdd(out, t * (1.f / (float)NN));
    }
}

extern "C" void kernel_launch(void* const* d_in, const int* in_sizes, int n_in,
                              void* d_out, int out_size, void* d_ws, size_t ws_size,
                              hipStream_t stream) {
    const float* E      = (const float*)d_in[0];
    const float* Wq     = (const float*)d_in[1];
    const float* Wk     = (const float*)d_in[2];
    const float* Wv     = (const float*)d_in[3];
    const float* ca     = (const float*)d_in[4];
    const float* cp     = (const float*)d_in[5];
    const float* W1     = (const float*)d_in[6];
    const float* b1     = (const float*)d_in[7];
    const float* W2     = (const float*)d_in[8];
    const float* b2     = (const float*)d_in[9];
    const float* demo   = (const float*)d_in[10];
    const float* ht     = (const float*)d_in[11];
    const float* evt    = (const float*)d_in[12];
    const float* labels = (const float*)d_in[13];
    const int*   codes  = (const int*)d_in[14];
    const int*   lens   = (const int*)d_in[15];
    float* out = (float*)d_out;

    unsigned short* Mx   = (unsigned short*)d_ws;                          // 128 KB
    unsigned short* W1eT = (unsigned short*)((char*)d_ws + 131072);        // 704 KB
    unsigned short* Rbf  = (unsigned short*)((char*)d_ws + 851968);        // 1 MB

    hipLaunchKernelGGL(k_init, dim3(1), dim3(64), 0, stream, ca, cp, out);
    hipLaunchKernelGGL(k_M,    dim3(DD), dim3(DD), 0, stream, Wq, Wk, Mx);
    hipLaunchKernelGGL(k_prep, dim3(352, 4), dim3(256), 0, stream, Wv, W1, W1eT);
    hipLaunchKernelGGL(k_main, dim3(NN), dim3(512), 0, stream,
                       E, ht, evt, codes, lens, ca, cp, Mx, Rbf);
    hipLaunchKernelGGL(k_mlp,  dim3(NN / 16), dim3(256), 0, stream,
                       demo, labels, b1, W2, b2, Rbf, W1eT, out);
}

// Round 4
// 263.763 us; speedup vs baseline: 3.9136x; 1.2843x over previous
//
#include <hip/hip_runtime.h>
#include <hip/hip_bf16.h>
#include <math.h>
#include <stdint.h>

#define VV 20000
#define LL 128
#define DD 256
#define DEMO_ 70
#define HID_ 1024
#define NN 2048

typedef __attribute__((ext_vector_type(8))) short short8;
typedef __attribute__((ext_vector_type(4))) float f32x4;

// ---- bf16 helpers ----
__device__ __forceinline__ float bf2f(uint32_t u) {
    union { uint32_t u; float f; } c; c.u = u << 16; return c.f;
}
__device__ __forceinline__ uint32_t f2bf(float f) {
    union { float f; uint32_t u; } c; c.f = f;
    return (c.u + 0x7fffu + ((c.u >> 16) & 1u)) >> 16;   // RNE
}

// swizzled halfword offset inside a [128][256] bf16 LDS tile
__device__ __forceinline__ int sw_off(int row, int col) {
    return (row << 8) + ((((col >> 3) ^ (row & 7)) << 3) | (col & 7));
}

// ---- kernel 0: zero z[2048], set out = reg_loss ----
__global__ __launch_bounds__(256) void k_init(const float* ca, const float* cp,
                                              float* z, float* out) {
    int idx = blockIdx.x * 256 + threadIdx.x;
    z[idx] = 0.f;
    if (idx == 0) out[0] = ca[0] * ca[0] + cp[0] * cp[0];
}

// ---- kernel 1: Mx = Wq @ Wk^T -> frag-major bf16 for k_main B-operand ----
__global__ __launch_bounds__(256) void k_M(const float* __restrict__ Wq,
                                           const float* __restrict__ Wk,
                                           unsigned short* __restrict__ Mxf) {
    __shared__ float wq_s[DD];
    int e = blockIdx.x, t = threadIdx.x;
    wq_s[t] = Wq[(size_t)e * DD + t];
    __syncthreads();
    const float4* wk4 = (const float4*)(Wk + (size_t)t * DD);
    const float4* wq4 = (const float4*)wq_s;
    float4 acc = make_float4(0.f, 0.f, 0.f, 0.f);
    for (int c = 0; c < DD / 4; ++c) {
        float4 a = wq4[c]; float4 b = wk4[c];
        acc.x += a.x * b.x; acc.y += a.y * b.y;
        acc.z += a.z * b.z; acc.w += a.w * b.w;
    }
    float val = acc.x + acc.y + acc.z + acc.w;
    // frag-major: frag = (n_tile)*8 + kk ; pos = (q*16 + m)*8 + j
    int frag = (e >> 4) * 8 + (t >> 5);
    int pos  = (((t >> 3) & 3) * 16 + (e & 15)) * 8 + (t & 7);
    Mxf[(size_t)frag * 512 + pos] = (unsigned short)f2bf(val);
}

// ---- kernel 2: W1eff -> frag-major bf16 [64 h-tiles][11 kk] ----
__global__ __launch_bounds__(256) void k_prep(const float* __restrict__ Wv,
                                              const float* __restrict__ W1,
                                              unsigned short* __restrict__ W1f) {
    __shared__ float wv_s[DD];
    int k = blockIdx.x, t = threadIdx.x;
    int h = t + 256 * blockIdx.y;
    float val;
    if (k >= 326) {
        val = 0.f;
    } else if (k < DEMO_) {
        val = W1[(size_t)k * HID_ + h];
    } else {
        int e = k - DEMO_;
        wv_s[t] = Wv[(size_t)e * DD + t];
        __syncthreads();
        float acc = 0.f;
        for (int n = 0; n < DD; ++n)
            acc += wv_s[n] * W1[(size_t)(DEMO_ + n) * HID_ + h];
        val = acc;
    }
    int frag = (h >> 4) * 11 + (k >> 5);
    int pos  = (((k >> 3) & 3) * 16 + (h & 15)) * 8 + (k & 7);
    W1f[(size_t)frag * 512 + pos] = (unsigned short)f2bf(val);
}

// ---- kernel 3: per-sample attention+pooling -> rp (bf16). 512 thr, 2 blocks/CU ----
__global__ __launch_bounds__(512, 4) void k_main(
    const float* __restrict__ E,
    const float* __restrict__ ht,  const float* __restrict__ evt_t,
    const int* __restrict__ codes, const int* __restrict__ lens,
    const float* __restrict__ ca_p, const float* __restrict__ cp_p,
    const unsigned short* __restrict__ Mxf,
    unsigned short* __restrict__ Rbf)
{
    __shared__ __align__(16) unsigned short emb_u[LL * DD];   // 64 KB; H overwrites in place
    __shared__ float times_s[LL];
    __shared__ int   codes_s[LL];
    __shared__ float w_s[LL];
    __shared__ float apart[8][LL];      // 4 KB
    __shared__ float rp_part[8][DD];    // 8 KB
    __shared__ float asum[LL];

    const int n = blockIdx.x;
    const int tid = threadIdx.x, wv = tid >> 6, ln = tid & 63;
    const int q = ln >> 4, m = ln & 15;
    const int len = lens[n];
    const int it_n = (len + 15) >> 4;
    const float ca = ca_p[0], cp = cp_p[0];
    const float evt = evt_t[n];

    ((float*)apart)[tid]          = 0.f;
    ((float*)apart)[tid + 512]    = 0.f;
    ((float*)rp_part)[tid]        = 0.f;
    ((float*)rp_part)[tid + 512]  = 0.f;
    ((float*)rp_part)[tid + 1024] = 0.f;
    ((float*)rp_part)[tid + 1536] = 0.f;
    if (tid < LL) {
        w_s[tid] = 0.f;
        if (tid < len) {
            times_s[tid] = ht[(size_t)n * LL + tid];
            codes_s[tid] = codes[(size_t)n * LL + tid];
        }
    }
    __syncthreads();

    // ---- pooling weights (wave 0)
    if (wv == 0) {
        float u0 = (ln      < len) ? cp * (times_s[ln]      - evt) : 0.f;
        float u1 = (ln + 64 < len) ? cp * (times_s[ln + 64] - evt) : 0.f;
        float e0 = (ln      < len) ? __expf(u0) : 0.f;
        float e1 = (ln + 64 < len) ? __expf(u1) : 0.f;
        float sm = e0 + e1;
        for (int o = 32; o; o >>= 1) sm += __shfl_xor(sm, o, 64);
        float inv = 1.f / sm;
        if (ln      < len) w_s[ln]      = e0 * inv;
        if (ln + 64 < len) w_s[ln + 64] = e1 * inv;
    }

    // ---- gather E rows -> swizzled bf16 LDS, 4 rows in flight per wave
    for (int l0 = wv; l0 < len; l0 += 32) {
        float4 v[4];
        #pragma unroll
        for (int u = 0; u < 4; ++u) {
            int l = l0 + u * 8;
            if (l < len)
                v[u] = ((const float4*)(E + (size_t)codes_s[l] * DD))[ln];
        }
        #pragma unroll
        for (int u = 0; u < 4; ++u) {
            int l = l0 + u * 8;
            if (l < len)
                *(uint2*)&emb_u[sw_off(l, 4 * ln)] =
                    make_uint2(f2bf(v[u].x) | (f2bf(v[u].y) << 16),
                               f2bf(v[u].z) | (f2bf(v[u].w) << 16));
        }
    }
    __syncthreads();

    // ---- phase B: H = emb @ Mx^T, overwriting emb tile-by-tile.
    // wave wv owns H cols [32wv, 32wv+32); coalesced frag-major Mx loads.
    short8 bB[2][8];
    #pragma unroll
    for (int nt = 0; nt < 2; ++nt)
        #pragma unroll
        for (int kk = 0; kk < 8; ++kk)
            bB[nt][kk] = *(const short8*)(Mxf + (size_t)((wv * 2 + nt) * 8 + kk) * 512 + ln * 8);

    short8 aC[8];                        // cached A-frags for row tile wv (emb rows 16wv..16wv+15)
    for (int it = 0; it < it_n; ++it) {
        f32x4 h0 = (f32x4)0.f, h1 = (f32x4)0.f;
        #pragma unroll
        for (int kk = 0; kk < 8; ++kk) {
            short8 af = *(const short8*)&emb_u[sw_off(it * 16 + m, kk * 32 + q * 8)];
            if (it == wv) aC[kk] = af;   // wave-uniform
            h0 = __builtin_amdgcn_mfma_f32_16x16x32_bf16(af, bB[0][kk], h0, 0, 0, 0);
            h1 = __builtin_amdgcn_mfma_f32_16x16x32_bf16(af, bB[1][kk], h1, 0, 0, 0);
        }
        __syncthreads();                 // all waves done READING emb tile it
        #pragma unroll
        for (int r = 0; r < 4; ++r) {
            int row = it * 16 + q * 4 + r;
            emb_u[sw_off(row, wv * 32 + m)]      = (unsigned short)f2bf(h0[r]);
            emb_u[sw_off(row, wv * 32 + 16 + m)] = (unsigned short)f2bf(h1[r]);
        }
    }
    __syncthreads();                     // H fully materialized

    // ---- phase C: wave wv owns row tile it=wv; S in registers
    if (wv < it_n) {
        f32x4 sac[8];
        #pragma unroll
        for (int jt = 0; jt < 8; ++jt) sac[jt] = (f32x4)0.f;
        for (int jt = 0; jt < it_n; ++jt) {
            #pragma unroll
            for (int kk = 0; kk < 8; ++kk) {
                short8 bH = *(const short8*)&emb_u[sw_off(jt * 16 + m, kk * 32 + q * 8)];
                sac[jt] = __builtin_amdgcn_mfma_f32_16x16x32_bf16(aC[kk], bH, sac[jt], 0, 0, 0);
            }
        }
        int i_base = wv * 16 + q * 4;
        float ti[4]; bool vR[4]; float rowsum[4];
        #pragma unroll
        for (int r = 0; r < 4; ++r) {
            vR[r] = (i_base + r) < len;
            ti[r] = times_s[i_base + r];
            rowsum[r] = 0.f;
        }
        for (int jt = 0; jt < it_n; ++jt) {
            int jcol = jt * 16 + m;
            bool vC = jcol < len;
            float tj = times_s[jcol];
            #pragma unroll
            for (int r = 0; r < 4; ++r) {
                float arg = sac[jt][r] * 0.0625f - ca * fabsf(ti[r] - tj);
                float p = (vR[r] && vC) ? __expf(arg) : 0.f;
                sac[jt][r] = p;
                rowsum[r] += p;
            }
        }
        #pragma unroll
        for (int r = 0; r < 4; ++r) {
            float s = rowsum[r];
            s += __shfl_xor(s, 1, 64); s += __shfl_xor(s, 2, 64);
            s += __shfl_xor(s, 4, 64); s += __shfl_xor(s, 8, 64);
            rowsum[r] = s;
        }
        float sc[4];
        #pragma unroll
        for (int r = 0; r < 4; ++r)
            sc[r] = (vR[r] && rowsum[r] > 0.f) ? w_s[i_base + r] / rowsum[r] : 0.f;
        for (int jt = 0; jt < it_n; ++jt) {
            float v = sc[0] * sac[jt][0] + sc[1] * sac[jt][1]
                    + sc[2] * sac[jt][2] + sc[3] * sac[jt][3];
            v += __shfl_xor(v, 16, 64);
            v += __shfl_xor(v, 32, 64);
            if (q == 0) apart[wv][jt * 16 + m] = v;
        }
    }
    __syncthreads();

    if (tid < LL)
        asum[tid] = apart[0][tid] + apart[1][tid] + apart[2][tid] + apart[3][tid]
                  + apart[4][tid] + apart[5][tid] + apart[6][tid] + apart[7][tid];
    __syncthreads();

    // ---- phase D: rp[e] = sum_j a_j * emb[j][e], from aC registers.
    // lane (q,m) of wave wv holds emb[16wv+m][32kk+8q+j], j=0..7
    if (wv < it_n) {
        float aw = asum[wv * 16 + m];
        #pragma unroll
        for (int kk = 0; kk < 8; ++kk) {
            float v[8];
            #pragma unroll
            for (int j = 0; j < 8; ++j)
                v[j] = aw * bf2f((uint32_t)(unsigned short)aC[kk][j]);
            #pragma unroll
            for (int o = 1; o <= 8; o <<= 1)
                #pragma unroll
                for (int j = 0; j < 8; ++j)
                    v[j] += __shfl_xor(v[j], o, 64);
            if (m < 8)
                rp_part[wv][kk * 32 + q * 8 + m] = v[m];
        }
    }
    __syncthreads();
    if (tid < DD) {
        float r = rp_part[0][tid] + rp_part[1][tid] + rp_part[2][tid] + rp_part[3][tid]
                + rp_part[4][tid] + rp_part[5][tid] + rp_part[6][tid] + rp_part[7][tid];
        Rbf[(size_t)n * DD + tid] = (unsigned short)f2bf(r);
    }
}

// ---- kernel 4: batched MLP partial-z. grid (NN/16, 4); block = 16 samples x 256 hidden ----
__global__ __launch_bounds__(256) void k_mlp(
    const float* __restrict__ demo,
    const float* __restrict__ b1,   const float* __restrict__ W2,
    const unsigned short* __restrict__ Rbf,
    const unsigned short* __restrict__ W1f,
    float* __restrict__ z)
{
    __shared__ __align__(16) unsigned short xs[16][360];
    __shared__ float W2s[256];
    __shared__ float b1s[256];
    __shared__ float wred[4][16];

    const int tid = threadIdx.x, wv = tid >> 6, ln = tid & 63;
    const int q = ln >> 4, m = ln & 15;
    const int s0 = blockIdx.x * 16;
    const int by = blockIdx.y;
    const int hbase = by * 256;

    W2s[tid] = W2[hbase + tid];
    b1s[tid] = b1[hbase + tid];
    for (int s = 0; s < 16; ++s) {
        if (tid < DEMO_) xs[s][tid] = (unsigned short)f2bf(demo[(size_t)(s0 + s) * DEMO_ + tid]);
        xs[s][DEMO_ + tid] = Rbf[(size_t)(s0 + s) * DD + tid];
        if (tid < 34) xs[s][326 + tid] = 0;
    }
    __syncthreads();

    f32x4 cacc[4];
    #pragma unroll
    for (int ntl = 0; ntl < 4; ++ntl) cacc[ntl] = (f32x4)0.f;

    for (int kk = 0; kk < 11; ++kk) {
        short8 af = *(const short8*)&xs[m][kk * 32 + q * 8];
        #pragma unroll
        for (int ntl = 0; ntl < 4; ++ntl) {
            int frag = (by * 16 + wv * 4 + ntl) * 11 + kk;
            short8 bfd = *(const short8*)(W1f + (size_t)frag * 512 + ln * 8);
            cacc[ntl] = __builtin_amdgcn_mfma_f32_16x16x32_bf16(af, bfd, cacc[ntl], 0, 0, 0);
        }
    }

    float ls0 = 0.f, ls1 = 0.f, ls2 = 0.f, ls3 = 0.f;
    #pragma unroll
    for (int ntl = 0; ntl < 4; ++ntl) {
        int hl = wv * 64 + ntl * 16 + m;
        float bb = b1s[hl], w2v = W2s[hl];
        ls0 += fmaxf(cacc[ntl][0] + bb, 0.f) * w2v;
        ls1 += fmaxf(cacc[ntl][1] + bb, 0.f) * w2v;
        ls2 += fmaxf(cacc[ntl][2] + bb, 0.f) * w2v;
        ls3 += fmaxf(cacc[ntl][3] + bb, 0.f) * w2v;
    }
    #pragma unroll
    for (int o = 1; o <= 8; o <<= 1) {
        ls0 += __shfl_xor(ls0, o, 64); ls1 += __shfl_xor(ls1, o, 64);
        ls2 += __shfl_xor(ls2, o, 64); ls3 += __shfl_xor(ls3, o, 64);
    }
    if (m == 0) {
        wred[wv][q * 4 + 0] = ls0; wred[wv][q * 4 + 1] = ls1;
        wred[wv][q * 4 + 2] = ls2; wred[wv][q * 4 + 3] = ls3;
    }
    __syncthreads();
    if (tid < 16)
        atomicAdd(&z[s0 + tid], wred[0][tid] + wred[1][tid] + wred[2][tid] + wred[3][tid]);
}

// ---- kernel 5: BCE loss over z ----
__global__ __launch_bounds__(256) void k_loss(const float* __restrict__ labels,
                                              const float* __restrict__ b2,
                                              const float* __restrict__ z,
                                              float* __restrict__ out) {
    __shared__ float red[4];
    int tid = threadIdx.x, wv = tid >> 6;
    int i = blockIdx.x * 256 + tid;
    float zz = z[i] + b2[0];
    float y = labels[i];
    float lg = log1pf(__expf(-fabsf(zz)));
    float loss = 2.f * y * (fmaxf(-zz, 0.f) + lg) + (1.f - y) * (fmaxf(zz, 0.f) + lg);
    for (int o = 32; o; o >>= 1) loss += __shfl_xor(loss, o, 64);
    if ((tid & 63) == 0) red[wv] = loss;
    __syncthreads();
    if (tid == 0)
        atomicAdd(out, (red[0] + red[1] + red[2] + red[3]) * (1.f / (float)NN));
}

extern "C" void kernel_launch(void* const* d_in, const int* in_sizes, int n_in,
                              void* d_out, int out_size, void* d_ws, size_t ws_size,
                              hipStream_t stream) {
    const float* E      = (const float*)d_in[0];
    const float* Wq     = (const float*)d_in[1];
    const float* Wk     = (const float*)d_in[2];
    const float* Wv     = (const float*)d_in[3];
    const float* ca     = (const float*)d_in[4];
    const float* cp     = (const float*)d_in[5];
    const float* W1     = (const float*)d_in[6];
    const float* b1     = (const float*)d_in[7];
    const float* W2     = (const float*)d_in[8];
    const float* b2     = (const float*)d_in[9];
    const float* demo   = (const float*)d_in[10];
    const float* ht     = (const float*)d_in[11];
    const float* evt    = (const float*)d_in[12];
    const float* labels = (const float*)d_in[13];
    const int*   codes  = (const int*)d_in[14];
    const int*   lens   = (const int*)d_in[15];
    float* out = (float*)d_out;

    unsigned short* Mxf = (unsigned short*)d_ws;                           // 128 KB
    unsigned short* W1f = (unsigned short*)((char*)d_ws + 131072);         // 704 KB
    unsigned short* Rbf = (unsigned short*)((char*)d_ws + 851968);         // 1 MB
    float*          zar = (float*)((char*)d_ws + 1900544);                 // 8 KB

    hipLaunchKernelGGL(k_init, dim3(NN / 256), dim3(256), 0, stream, ca, cp, zar, out);
    hipLaunchKernelGGL(k_M,    dim3(DD), dim3(DD), 0, stream, Wq, Wk, Mxf);
    hipLaunchKernelGGL(k_prep, dim3(352, 4), dim3(256), 0, stream, Wv, W1, W1f);
    hipLaunchKernelGGL(k_main, dim3(NN), dim3(512), 0, stream,
                       E, ht, evt, codes, lens, ca, cp, Mxf, Rbf);
    hipLaunchKernelGGL(k_mlp,  dim3(NN / 16, 4), dim3(256), 0, stream,
                       demo, b1, W2, Rbf, W1f, zar);
    hipLaunchKernelGGL(k_loss, dim3(NN / 256), dim3(256), 0, stream, labels, b2, zar, out);
}

// Round 5
// 227.809 us; speedup vs baseline: 4.5313x; 1.1578x over previous
//
#include <hip/hip_runtime.h>
#include <hip/hip_bf16.h>
#include <math.h>
#include <stdint.h>

#define VV 20000
#define LL 128
#define DD 256
#define DEMO_ 70
#define HID_ 1024
#define NN 2048

typedef __attribute__((ext_vector_type(8))) short short8;
typedef __attribute__((ext_vector_type(4))) float f32x4;

// ---- bf16 helpers ----
__device__ __forceinline__ float bf2f(uint32_t u) {
    union { uint32_t u; float f; } c; c.u = u << 16; return c.f;
}
__device__ __forceinline__ uint32_t f2bf(float f) {
    union { float f; uint32_t u; } c; c.f = f;
    return (c.u + 0x7fffu + ((c.u >> 16) & 1u)) >> 16;   // RNE
}

// swizzled halfword offset inside a [128][256] bf16 LDS tile
__device__ __forceinline__ int sw_off(int row, int col) {
    return (row << 8) + ((((col >> 3) ^ (row & 7)) << 3) | (col & 7));
}

// ---- fused pre-kernel: k_M (blocks 0..255) + k_prep (256..1663) +
//      length-sort (1664) + init (1665) ----
__global__ __launch_bounds__(256) void k_pre(
    const float* __restrict__ Wq, const float* __restrict__ Wk,
    const float* __restrict__ Wv, const float* __restrict__ W1,
    const float* __restrict__ ca, const float* __restrict__ cp,
    const int* __restrict__ lens,
    unsigned short* __restrict__ Mxf, unsigned short* __restrict__ W1f,
    int* __restrict__ order, float* __restrict__ z, float* __restrict__ out)
{
    __shared__ float sm[DD];
    __shared__ int cnt[9], off[9], cur[9];
    const int b = blockIdx.x, t = threadIdx.x;

    if (b < 256) {
        // ---- Mx = Wq @ Wk^T -> frag-major bf16 ----
        int e = b;
        sm[t] = Wq[(size_t)e * DD + t];
        __syncthreads();
        const float4* wk4 = (const float4*)(Wk + (size_t)t * DD);
        const float4* wq4 = (const float4*)sm;
        float4 acc = make_float4(0.f, 0.f, 0.f, 0.f);
        for (int c = 0; c < DD / 4; ++c) {
            float4 a = wq4[c]; float4 bb = wk4[c];
            acc.x += a.x * bb.x; acc.y += a.y * bb.y;
            acc.z += a.z * bb.z; acc.w += a.w * bb.w;
        }
        float val = acc.x + acc.y + acc.z + acc.w;
        int frag = (e >> 4) * 8 + (t >> 5);
        int pos  = (((t >> 3) & 3) * 16 + (e & 15)) * 8 + (t & 7);
        Mxf[(size_t)frag * 512 + pos] = (unsigned short)f2bf(val);
    } else if (b < 256 + 1408) {
        // ---- W1eff -> frag-major bf16 ----
        int idx = b - 256;
        int k = idx % 352, by = idx / 352;
        int h = t + 256 * by;
        float val;
        if (k >= 326) {
            val = 0.f;
        } else if (k < DEMO_) {
            val = W1[(size_t)k * HID_ + h];
        } else {
            int e = k - DEMO_;
            sm[t] = Wv[(size_t)e * DD + t];
            __syncthreads();
            float acc = 0.f;
            for (int n = 0; n < DD; ++n)
                acc += sm[n] * W1[(size_t)(DEMO_ + n) * HID_ + h];
            val = acc;
        }
        int frag = (h >> 4) * 11 + (k >> 5);
        int pos  = (((k >> 3) & 3) * 16 + (h & 15)) * 8 + (k & 7);
        W1f[(size_t)frag * 512 + pos] = (unsigned short)f2bf(val);
    } else if (b == 1664) {
        // ---- LPT order: bucket samples by it_n descending ----
        if (t < 9) cnt[t] = 0;
        __syncthreads();
        for (int i = t; i < NN; i += 256)
            atomicAdd(&cnt[(lens[i] + 15) >> 4], 1);
        __syncthreads();
        if (t == 0) {
            int acc = 0;
            for (int k = 8; k >= 1; --k) { off[k] = acc; acc += cnt[k]; cur[k] = off[k]; }
        }
        __syncthreads();
        for (int i = t; i < NN; i += 256) {
            int key = (lens[i] + 15) >> 4;
            int pos = atomicAdd(&cur[key], 1);
            order[pos] = i;
        }
    } else {
        // ---- init: z = 0, out = reg_loss ----
        for (int i = t; i < NN; i += 256) z[i] = 0.f;
        if (t == 0) out[0] = ca[0] * ca[0] + cp[0] * cp[0];
    }
}

// ---- kernel 2: per-sample attention+pooling -> rp (bf16). 512 thr, 2 blocks/CU ----
__global__ __launch_bounds__(512, 4) void k_main(
    const float* __restrict__ E,
    const float* __restrict__ ht,  const float* __restrict__ evt_t,
    const int* __restrict__ codes, const int* __restrict__ lens,
    const float* __restrict__ ca_p, const float* __restrict__ cp_p,
    const unsigned short* __restrict__ Mxf,
    const int* __restrict__ order,
    unsigned short* __restrict__ Rbf)
{
    __shared__ __align__(16) unsigned short emb_u[LL * DD];   // 64 KB; H overwrites in place
    __shared__ float times_s[LL];
    __shared__ int   codes_s[LL];
    __shared__ float w_s[LL];
    __shared__ float apart[8][LL];      // 4 KB
    __shared__ float rp_part[8][DD];    // 8 KB
    __shared__ float asum[LL];

    const int n = order[blockIdx.x];
    const int tid = threadIdx.x, wv = tid >> 6, ln = tid & 63;
    const int q = ln >> 4, m = ln & 15;
    const int len = lens[n];
    const int it_n = (len + 15) >> 4;
    const float ca = ca_p[0], cp = cp_p[0];
    const float evt = evt_t[n];

    // ---- preload B-frags for phase B (in flight across gather)
    short8 bB[2][8];
    #pragma unroll
    for (int nt = 0; nt < 2; ++nt)
        #pragma unroll
        for (int kk = 0; kk < 8; ++kk)
            bB[nt][kk] = *(const short8*)(Mxf + (size_t)((wv * 2 + nt) * 8 + kk) * 512 + ln * 8);

    // ---- stage times/codes (waves 0-1); pooling weights from global (wave 0)
    if (tid < LL) {
        bool v = tid < len;
        times_s[tid] = v ? ht[(size_t)n * LL + tid] : 0.f;
        codes_s[tid] = v ? codes[(size_t)n * LL + tid] : 0;
    }
    if (wv == 0) {
        float t0 = (ln      < len) ? ht[(size_t)n * LL + ln]      : 0.f;
        float t1 = (ln + 64 < len) ? ht[(size_t)n * LL + ln + 64] : 0.f;
        float e0 = (ln      < len) ? __expf(cp * (t0 - evt)) : 0.f;
        float e1 = (ln + 64 < len) ? __expf(cp * (t1 - evt)) : 0.f;
        float smm = e0 + e1;
        for (int o = 32; o; o >>= 1) smm += __shfl_xor(smm, o, 64);
        float inv = 1.f / smm;
        if (ln      < len) w_s[ln]      = e0 * inv;
        if (ln + 64 < len) w_s[ln + 64] = e1 * inv;
    }
    __syncthreads();

    // ---- gather E rows -> swizzled bf16 LDS, 4 rows in flight per wave
    for (int l0 = wv; l0 < len; l0 += 32) {
        float4 v[4];
        #pragma unroll
        for (int u = 0; u < 4; ++u) {
            int l = l0 + u * 8;
            if (l < len)
                v[u] = ((const float4*)(E + (size_t)codes_s[l] * DD))[ln];
        }
        #pragma unroll
        for (int u = 0; u < 4; ++u) {
            int l = l0 + u * 8;
            if (l < len)
                *(uint2*)&emb_u[sw_off(l, 4 * ln)] =
                    make_uint2(f2bf(v[u].x) | (f2bf(v[u].y) << 16),
                               f2bf(v[u].z) | (f2bf(v[u].w) << 16));
        }
    }
    __syncthreads();

    // ---- phase B: H = emb @ Mx^T, overwriting emb tile-by-tile
    short8 aC[8];                        // cached A-frags for row tile wv
    for (int it = 0; it < it_n; ++it) {
        f32x4 h0 = (f32x4)0.f, h1 = (f32x4)0.f;
        #pragma unroll
        for (int kk = 0; kk < 8; ++kk) {
            short8 af = *(const short8*)&emb_u[sw_off(it * 16 + m, kk * 32 + q * 8)];
            if (it == wv) aC[kk] = af;   // wave-uniform
            h0 = __builtin_amdgcn_mfma_f32_16x16x32_bf16(af, bB[0][kk], h0, 0, 0, 0);
            h1 = __builtin_amdgcn_mfma_f32_16x16x32_bf16(af, bB[1][kk], h1, 0, 0, 0);
        }
        __syncthreads();                 // all waves done reading emb tile it
        #pragma unroll
        for (int r = 0; r < 4; ++r) {
            int row = it * 16 + q * 4 + r;
            emb_u[sw_off(row, wv * 32 + m)]      = (unsigned short)f2bf(h0[r]);
            emb_u[sw_off(row, wv * 32 + 16 + m)] = (unsigned short)f2bf(h1[r]);
        }
    }
    __syncthreads();                     // H fully materialized

    // ---- phase C: wave wv owns row tile it=wv; S in registers
    if (wv < it_n) {
        f32x4 sac[8];
        #pragma unroll
        for (int jt = 0; jt < 8; ++jt) sac[jt] = (f32x4)0.f;
        for (int jt = 0; jt < it_n; ++jt) {
            #pragma unroll
            for (int kk = 0; kk < 8; ++kk) {
                short8 bH = *(const short8*)&emb_u[sw_off(jt * 16 + m, kk * 32 + q * 8)];
                sac[jt] = __builtin_amdgcn_mfma_f32_16x16x32_bf16(aC[kk], bH, sac[jt], 0, 0, 0);
            }
        }
        int i_base = wv * 16 + q * 4;
        float ti[4]; bool vR[4]; float rowsum[4];
        #pragma unroll
        for (int r = 0; r < 4; ++r) {
            vR[r] = (i_base + r) < len;
            ti[r] = times_s[i_base + r];
            rowsum[r] = 0.f;
        }
        for (int jt = 0; jt < it_n; ++jt) {
            int jcol = jt * 16 + m;
            bool vC = jcol < len;
            float tj = times_s[jcol];
            #pragma unroll
            for (int r = 0; r < 4; ++r) {
                float arg = sac[jt][r] * 0.0625f - ca * fabsf(ti[r] - tj);
                float p = (vR[r] && vC) ? __expf(arg) : 0.f;
                sac[jt][r] = p;
                rowsum[r] += p;
            }
        }
        #pragma unroll
        for (int r = 0; r < 4; ++r) {
            float s = rowsum[r];
            s += __shfl_xor(s, 1, 64); s += __shfl_xor(s, 2, 64);
            s += __shfl_xor(s, 4, 64); s += __shfl_xor(s, 8, 64);
            rowsum[r] = s;
        }
        float sc[4];
        #pragma unroll
        for (int r = 0; r < 4; ++r)
            sc[r] = (vR[r] && rowsum[r] > 0.f) ? w_s[i_base + r] / rowsum[r] : 0.f;
        for (int jt = 0; jt < it_n; ++jt) {
            float v = sc[0] * sac[jt][0] + sc[1] * sac[jt][1]
                    + sc[2] * sac[jt][2] + sc[3] * sac[jt][3];
            v += __shfl_xor(v, 16, 64);
            v += __shfl_xor(v, 32, 64);
            if (q == 0) apart[wv][jt * 16 + m] = v;
        }
    }
    __syncthreads();

    if (tid < LL) {
        float s = 0.f;
        for (int r = 0; r < it_n; ++r) s += apart[r][tid];
        asum[tid] = s;
    }
    __syncthreads();

    // ---- phase D: rp[e] = sum_j a_j * emb[j][e], from aC registers
    if (wv < it_n) {
        float aw = asum[wv * 16 + m];
        #pragma unroll
        for (int kk = 0; kk < 8; ++kk) {
            float v[8];
            #pragma unroll
            for (int j = 0; j < 8; ++j)
                v[j] = aw * bf2f((uint32_t)(unsigned short)aC[kk][j]);
            #pragma unroll
            for (int o = 1; o <= 8; o <<= 1)
                #pragma unroll
                for (int j = 0; j < 8; ++j)
                    v[j] += __shfl_xor(v[j], o, 64);
            if (m < 8)
                rp_part[wv][kk * 32 + q * 8 + m] = v[m];
        }
    }
    __syncthreads();
    if (tid < DD) {
        float r = 0.f;
        for (int t = 0; t < it_n; ++t) r += rp_part[t][tid];
        Rbf[(size_t)n * DD + tid] = (unsigned short)f2bf(r);
    }
}

// ---- kernel 3: batched MLP partial-z. grid (NN/16, 4) ----
__global__ __launch_bounds__(256) void k_mlp(
    const float* __restrict__ demo,
    const float* __restrict__ b1,   const float* __restrict__ W2,
    const unsigned short* __restrict__ Rbf,
    const unsigned short* __restrict__ W1f,
    float* __restrict__ z)
{
    __shared__ __align__(16) unsigned short xs[16][360];
    __shared__ float W2s[256];
    __shared__ float b1s[256];
    __shared__ float wred[4][16];

    const int tid = threadIdx.x, wv = tid >> 6, ln = tid & 63;
    const int q = ln >> 4, m = ln & 15;
    const int s0 = blockIdx.x * 16;
    const int by = blockIdx.y;
    const int hbase = by * 256;

    W2s[tid] = W2[hbase + tid];
    b1s[tid] = b1[hbase + tid];
    for (int s = 0; s < 16; ++s) {
        if (tid < DEMO_) xs[s][tid] = (unsigned short)f2bf(demo[(size_t)(s0 + s) * DEMO_ + tid]);
        xs[s][DEMO_ + tid] = Rbf[(size_t)(s0 + s) * DD + tid];
        if (tid < 34) xs[s][326 + tid] = 0;
    }
    __syncthreads();

    f32x4 cacc[4];
    #pragma unroll
    for (int ntl = 0; ntl < 4; ++ntl) cacc[ntl] = (f32x4)0.f;

    for (int kk = 0; kk < 11; ++kk) {
        short8 af = *(const short8*)&xs[m][kk * 32 + q * 8];
        #pragma unroll
        for (int ntl = 0; ntl < 4; ++ntl) {
            int frag = (by * 16 + wv * 4 + ntl) * 11 + kk;
            short8 bfd = *(const short8*)(W1f + (size_t)frag * 512 + ln * 8);
            cacc[ntl] = __builtin_amdgcn_mfma_f32_16x16x32_bf16(af, bfd, cacc[ntl], 0, 0, 0);
        }
    }

    float ls0 = 0.f, ls1 = 0.f, ls2 = 0.f, ls3 = 0.f;
    #pragma unroll
    for (int ntl = 0; ntl < 4; ++ntl) {
        int hl = wv * 64 + ntl * 16 + m;
        float bb = b1s[hl], w2v = W2s[hl];
        ls0 += fmaxf(cacc[ntl][0] + bb, 0.f) * w2v;
        ls1 += fmaxf(cacc[ntl][1] + bb, 0.f) * w2v;
        ls2 += fmaxf(cacc[ntl][2] + bb, 0.f) * w2v;
        ls3 += fmaxf(cacc[ntl][3] + bb, 0.f) * w2v;
    }
    #pragma unroll
    for (int o = 1; o <= 8; o <<= 1) {
        ls0 += __shfl_xor(ls0, o, 64); ls1 += __shfl_xor(ls1, o, 64);
        ls2 += __shfl_xor(ls2, o, 64); ls3 += __shfl_xor(ls3, o, 64);
    }
    if (m == 0) {
        wred[wv][q * 4 + 0] = ls0; wred[wv][q * 4 + 1] = ls1;
        wred[wv][q * 4 + 2] = ls2; wred[wv][q * 4 + 3] = ls3;
    }
    __syncthreads();
    if (tid < 16)
        atomicAdd(&z[s0 + tid], wred[0][tid] + wred[1][tid] + wred[2][tid] + wred[3][tid]);
}

// ---- kernel 4: BCE loss over z ----
__global__ __launch_bounds__(256) void k_loss(const float* __restrict__ labels,
                                              const float* __restrict__ b2,
                                              const float* __restrict__ z,
                                              float* __restrict__ out) {
    __shared__ float red[4];
    int tid = threadIdx.x, wv = tid >> 6;
    int i = blockIdx.x * 256 + tid;
    float zz = z[i] + b2[0];
    float y = labels[i];
    float lg = log1pf(__expf(-fabsf(zz)));
    float loss = 2.f * y * (fmaxf(-zz, 0.f) + lg) + (1.f - y) * (fmaxf(zz, 0.f) + lg);
    for (int o = 32; o; o >>= 1) loss += __shfl_xor(loss, o, 64);
    if ((tid & 63) == 0) red[wv] = loss;
    __syncthreads();
    if (tid == 0)
        atomicAdd(out, (red[0] + red[1] + red[2] + red[3]) * (1.f / (float)NN));
}

extern "C" void kernel_launch(void* const* d_in, const int* in_sizes, int n_in,
                              void* d_out, int out_size, void* d_ws, size_t ws_size,
                              hipStream_t stream) {
    const float* E      = (const float*)d_in[0];
    const float* Wq     = (const float*)d_in[1];
    const float* Wk     = (const float*)d_in[2];
    const float* Wv     = (const float*)d_in[3];
    const float* ca     = (const float*)d_in[4];
    const float* cp     = (const float*)d_in[5];
    const float* W1     = (const float*)d_in[6];
    const float* b1     = (const float*)d_in[7];
    const float* W2     = (const float*)d_in[8];
    const float* b2     = (const float*)d_in[9];
    const float* demo   = (const float*)d_in[10];
    const float* ht     = (const float*)d_in[11];
    const float* evt    = (const float*)d_in[12];
    const float* labels = (const float*)d_in[13];
    const int*   codes  = (const int*)d_in[14];
    const int*   lens   = (const int*)d_in[15];
    float* out = (float*)d_out;

    unsigned short* Mxf = (unsigned short*)d_ws;                           // 128 KB
    unsigned short* W1f = (unsigned short*)((char*)d_ws + 131072);         // 704 KB
    unsigned short* Rbf = (unsigned short*)((char*)d_ws + 851968);         // 1 MB
    float*          zar = (float*)((char*)d_ws + 1900544);                 // 8 KB
    int*            ord = (int*)((char*)d_ws + 1908736);                   // 8 KB

    hipLaunchKernelGGL(k_pre,  dim3(1666), dim3(256), 0, stream,
                       Wq, Wk, Wv, W1, ca, cp, lens, Mxf, W1f, ord, zar, out);
    hipLaunchKernelGGL(k_main, dim3(NN), dim3(512), 0, stream,
                       E, ht, evt, codes, lens, ca, cp, Mxf, ord, Rbf);
    hipLaunchKernelGGL(k_mlp,  dim3(NN / 16, 4), dim3(256), 0, stream,
                       demo, b1, W2, Rbf, W1f, zar);
    hipLaunchKernelGGL(k_loss, dim3(NN / 256), dim3(256), 0, stream, labels, b2, zar, out);
}